// Round 7
// baseline (589.433 us; speedup 1.0000x reference)
//
#include <hip/hip_runtime.h>
#include <stdint.h>

// QuantizedLinear: x[8,512,4096] fp32, W[11008,4096] int8-in-int32, scale[11008] fp32
#define M_DIM 4096
#define N_DIM 11008
#define K_DIM 4096

typedef int i32x4 __attribute__((ext_vector_type(4)));

// async global->LDS, 16 bytes/lane. LDS dest = wave-uniform base + lane*16.
static __device__ __forceinline__ void direct_load16(const void* gptr, void* ldsptr) {
    __builtin_amdgcn_global_load_lds(
        (const __attribute__((address_space(1))) void*)gptr,
        (__attribute__((address_space(3))) void*)ldsptr,
        16, 0, 0);
}

// ---- W: int32 in [-127,127] -> int8, 4 elems/thread, coalesced both sides
__global__ __launch_bounds__(256) void cvt_w_kernel(const int* __restrict__ w,
                                                    int8_t* __restrict__ o) {
    int t = blockIdx.x * 256 + threadIdx.x;
    const int4* w4 = (const int4*)w;
    int4 a = w4[t];
    ((unsigned*)o)[t] = (a.x & 255) | ((a.y & 255) << 8) | ((a.z & 255) << 16) | (a.w << 24);
}

// ---- x: fp32 -> int8, absmax-scaled, output in MFMA-FRAGMENT-TILED layout:
// Xq_t[mt][kt][lane][16B], mt=row/16, kt=k/64, lane = ((k%64)/16)*16 + row%16.
// A GEMM wave then loads one A-fragment as a single coalesced 1KB dwordx4.
__global__ __launch_bounds__(256) void quant_x_kernel(const float* __restrict__ x,
                                                      int8_t* __restrict__ xq,
                                                      float* __restrict__ xs) {
    __shared__ float wmax[4];
    const int row = blockIdx.x;
    const int t = threadIdx.x;
    const float4* xr = (const float4*)(x + (size_t)row * K_DIM);

    float4 v[4];
    float am = 0.0f;
#pragma unroll
    for (int p = 0; p < 4; p++) {
        v[p] = xr[p * 256 + t];
        am = fmaxf(am, fmaxf(fmaxf(fabsf(v[p].x), fabsf(v[p].y)),
                             fmaxf(fabsf(v[p].z), fabsf(v[p].w))));
    }
#pragma unroll
    for (int o = 32; o > 0; o >>= 1)
        am = fmaxf(am, __shfl_xor(am, o));
    if ((t & 63) == 0) wmax[t >> 6] = am;
    __syncthreads();
    am = fmaxf(fmaxf(wmax[0], wmax[1]), fmaxf(wmax[2], wmax[3]));

    const float inv = 127.0f / am;
    int* oq = (int*)xq;
    const int mt = row >> 4, ml = row & 15;
#pragma unroll
    for (int p = 0; p < 4; p++) {
        int qa = (int)rintf(v[p].x * inv);
        int qb = (int)rintf(v[p].y * inv);
        int qc = (int)rintf(v[p].z * inv);
        int qd = (int)rintf(v[p].w * inv);
        const int packed = (qa & 255) | ((qb & 255) << 8) | ((qc & 255) << 16) | (qd << 24);
        const int w0 = p * 256 + t;                     // k-word index 0..1023
        // int idx: tile (mt*64 + w0>>4) * 256 + lane*4 + word
        const int idx = (((mt << 6) + (w0 >> 4)) << 8)
                      + (((((w0 >> 2) & 3) << 4) | ml) << 2) + (w0 & 3);
        oq[idx] = packed;
    }
    if (t == 0) xs[row] = am * (1.0f / 127.0f);
}

// ---- GEMM: C = (Aq . Bq^T) * xs[m] * ws[n] ------------------------------
// 256x256 tile, 512 thr = 8 waves (2M x 4N), BK=64, 16x16x64 MFMA.
// r7 change: A (Xq) is NOT staged in LDS. Xq is pre-tiled so each A-frag is
// one coalesced 1KB global_load_dwordx4 -> operand regs (L2-resident: each
// XCD owns 2 m-panels = 2MB of Xq). LDS holds B only: 8 buffers x 16KB,
// depth-4 staging (stage target's last reader is 4 barriers back => race-
// free by construction). Per tile: 4 ds_read_b128 + 2 gload_lds + 32 MFMA +
// 8 A-frag global loads + ONE vmcnt(4) + ONE barrier.
// LDS traffic/tile/CU: 32KB reads + 16KB writes (was 128KB) -> LDS no
// longer co-bottleneck with the MFMA pipe.
//
// vmcnt: per iter issues [stageB(t+4) x2 ... A(t+1) x8]. wait vmcnt(4) at
// iter t retires through A(t) (and the older stageB(t+3)), leaving only
// stageB(t+4) in flight. So A(t) regs are complete before MFMA(t), and
// B(t) was forced complete at wait_{t-2} latest; barrier publishes stages.
//
// XCD mapping: xcd = orig&7 owns m_idx {2*xcd, 2*xcd+1}, sweeping all 43
// n-blocks per m-panel -> A panel L2-resident per XCD, B streams.

__global__ __launch_bounds__(512, 2) void gemm_i8_kernel(
    const int8_t* __restrict__ A,     // Xq tiled: [M/16][64][64][16B]
    const int8_t* __restrict__ B,     // [N][K] i8 row-major
    const float* __restrict__ xs,     // [M]
    const float* __restrict__ ws,     // [N]
    float* __restrict__ C)            // [M][N] fp32
{
    __shared__ __align__(16) int8_t Bs[8][256 * 64];   // 128 KiB, B only

    const int tid  = threadIdx.x;
    const int lane = tid & 63;
    const int wave = tid >> 6;         // 0..7
    const int wm   = wave >> 2;        // 0..1 -> 128 rows each
    const int wn   = wave & 3;         // 0..3 -> 64 cols each
    const int quad = lane >> 4;
    const int r16  = lane & 15;

    // XCD-locality mapping: grid 16x43=688 = 8 XCDs x 86. Each XCD gets
    // m_idx in {2*xcd, 2*xcd+1}, n sweeps 0..42 within each m panel.
    const int orig  = blockIdx.x + (blockIdx.y << 4);
    const int ix    = orig >> 3;                 // 0..85
    const int hi    = (ix >= 43) ? 1 : 0;
    const int m_idx = ((orig & 7) << 1) + hi;    // 0..15
    const int n_idx = ix - hi * 43;              // 0..42
    const int m0 = m_idx * 256;
    const int n0 = n_idx * 256;

    // B staging: thread t -> row t>>2 (+128 for 2nd instr), chunk slot t&3,
    // source chunk pre-XOR-swizzled (phys slot p holds chunk p ^ ((row>>1)&3)).
    const int srow   = tid >> 2;                       // 0..127
    const int schunk = (tid & 3) ^ ((tid >> 3) & 3);
    const int8_t* gB = B + (size_t)(n0 + srow) * K_DIM + schunk * 16;
    const size_t half2 = (size_t)128 * K_DIM;          // rows 128..255
    const int wb = wave * 1024;                        // wave-uniform LDS base

    // B read side: logical chunk = quad, physical = quad ^ ((row>>1)&3)
    const int fsw   = (r16 >> 1) & 3;
    const int b_off = (wn * 64 + r16) * 64 + ((quad ^ fsw) * 16);  // + j*1024

    // A tiled per-lane pointer: frag i, tile t at pA + i*65536 + t*1024
    const int8_t* pA = A + ((size_t)(m_idx * 16 + wm * 8)) * 65536 + lane * 16;

    i32x4 acc[8][4];
#pragma unroll
    for (int i = 0; i < 8; i++)
#pragma unroll
        for (int j = 0; j < 4; j++) acc[i][j] = (i32x4)(0);

    i32x4 af[8], bf[4];

#define STAGE_B(t, buf) do {                                                  \
        direct_load16(gB + (size_t)(t) * 64,         (char*)Bs[buf] + wb);    \
        direct_load16(gB + (size_t)(t) * 64 + half2, (char*)Bs[buf] + wb + 8192); \
    } while (0)

    // prologue: stage B tiles 0..3; load A(0) frags
    STAGE_B(0, 0); STAGE_B(1, 1); STAGE_B(2, 2); STAGE_B(3, 3);
#pragma unroll
    for (int i = 0; i < 8; i++)
        af[i] = *(const i32x4*)(pA + i * 65536);

    for (int t = 0; t < 64; ++t) {
        const int s = (t + 4 > 63) ? 63 : t + 4;       // tail: dummy restage
        STAGE_B(s, (t + 4) & 7);

        // forces A(t) + stageB(<=t+3) complete; leaves stageB(t+4) in flight
        asm volatile("s_waitcnt vmcnt(4)" ::: "memory");
        __builtin_amdgcn_s_barrier();

        const int8_t* bs = Bs[t & 7];
#pragma unroll
        for (int j = 0; j < 4; j++)
            bf[j] = *(const i32x4*)(bs + b_off + j * 1024);

        __builtin_amdgcn_s_setprio(1);
#pragma unroll
        for (int i = 0; i < 8; i++)
#pragma unroll
            for (int j = 0; j < 4; j++)
                acc[i][j] = __builtin_amdgcn_mfma_i32_16x16x64_i8(
                    af[i], bf[j], acc[i][j], 0, 0, 0);
        __builtin_amdgcn_s_setprio(0);

        if (t < 63) {
#pragma unroll
            for (int i = 0; i < 8; i++)
                af[i] = *(const i32x4*)(pA + i * 65536 + (size_t)(t + 1) * 1024);
        }
    }

#undef STAGE_B

    // epilogue: fp32 rescale by xs[m]*ws[n]; C/D frag: col=r16, row=quad*4+r
#pragma unroll
    for (int i = 0; i < 8; i++) {
        const int mrow = m0 + wm * 128 + i * 16 + quad * 4;
        float rsc[4];
#pragma unroll
        for (int r = 0; r < 4; r++) rsc[r] = xs[mrow + r];
#pragma unroll
        for (int j = 0; j < 4; j++) {
            const int n = n0 + wn * 64 + j * 16 + r16;
            const float sc = ws[n];
#pragma unroll
            for (int r = 0; r < 4; r++)
                C[(size_t)(mrow + r) * N_DIM + n] = (float)acc[i][j][r] * sc * rsc[r];
        }
    }
}

// ---- launcher ------------------------------------------------------------

extern "C" void kernel_launch(void* const* d_in, const int* in_sizes, int n_in,
                              void* d_out, int out_size, void* d_ws, size_t ws_size,
                              hipStream_t stream) {
    const float* x       = (const float*)d_in[0];   // [4096][4096]
    const int*   w_int   = (const int*)d_in[1];     // [11008][4096]
    const float* w_scale = (const float*)d_in[2];   // [11008]
    float*       out     = (float*)d_out;           // [4096][11008]

    // ws layout: Wq i8 (45,088,768 B) | Xq tiled i8 (16,777,216 B) | xs f32
    int8_t* wq = (int8_t*)d_ws;
    int8_t* xq = (int8_t*)((char*)d_ws + (size_t)N_DIM * K_DIM);
    float*  xs = (float*)((char*)d_ws + (size_t)N_DIM * K_DIM + (size_t)M_DIM * K_DIM);

    cvt_w_kernel<<<dim3(N_DIM * K_DIM / 4 / 256), dim3(256), 0, stream>>>(w_int, wq);
    quant_x_kernel<<<dim3(M_DIM), dim3(256), 0, stream>>>(x, xq, xs);
    gemm_i8_kernel<<<dim3(M_DIM / 256, N_DIM / 256), dim3(512), 0, stream>>>(xq, wq, xs, w_scale, out);
}

// Round 8
// 527.226 us; speedup vs baseline: 1.1180x; 1.1180x over previous
//
#include <hip/hip_runtime.h>
#include <stdint.h>

// QuantizedLinear: x[8,512,4096] fp32, W[11008,4096] int8-in-int32, scale[11008] fp32
#define M_DIM 4096
#define N_DIM 11008
#define K_DIM 4096

typedef int i32x4 __attribute__((ext_vector_type(4)));

// async global->LDS, 16 bytes/lane. LDS dest = wave-uniform base + lane*16.
static __device__ __forceinline__ void direct_load16(const void* gptr, void* ldsptr) {
    __builtin_amdgcn_global_load_lds(
        (const __attribute__((address_space(1))) void*)gptr,
        (__attribute__((address_space(3))) void*)ldsptr,
        16, 0, 0);
}

// ---- W: int32 in [-127,127] -> int8, 4 elems/thread, coalesced both sides
__global__ __launch_bounds__(256) void cvt_w_kernel(const int* __restrict__ w,
                                                    int8_t* __restrict__ o) {
    int t = blockIdx.x * 256 + threadIdx.x;
    const int4* w4 = (const int4*)w;
    int4 a = w4[t];
    ((unsigned*)o)[t] = (a.x & 255) | ((a.y & 255) << 8) | ((a.z & 255) << 16) | (a.w << 24);
}

// ---- x: fp32 -> int8 with per-row absmax scale (row-major output) -------
__global__ __launch_bounds__(256) void quant_x_kernel(const float* __restrict__ x,
                                                      int8_t* __restrict__ xq,
                                                      float* __restrict__ xs) {
    __shared__ float wmax[4];
    const int row = blockIdx.x;
    const int t = threadIdx.x;
    const float4* xr = (const float4*)(x + (size_t)row * K_DIM);

    float4 v[4];
    float am = 0.0f;
#pragma unroll
    for (int p = 0; p < 4; p++) {
        v[p] = xr[p * 256 + t];
        am = fmaxf(am, fmaxf(fmaxf(fabsf(v[p].x), fabsf(v[p].y)),
                             fmaxf(fabsf(v[p].z), fabsf(v[p].w))));
    }
#pragma unroll
    for (int o = 32; o > 0; o >>= 1)
        am = fmaxf(am, __shfl_xor(am, o));
    if ((t & 63) == 0) wmax[t >> 6] = am;
    __syncthreads();
    am = fmaxf(fmaxf(wmax[0], wmax[1]), fmaxf(wmax[2], wmax[3]));

    const float inv = 127.0f / am;
    int* oq = (int*)(xq + (size_t)row * K_DIM);
#pragma unroll
    for (int p = 0; p < 4; p++) {
        int qa = (int)rintf(v[p].x * inv);
        int qb = (int)rintf(v[p].y * inv);
        int qc = (int)rintf(v[p].z * inv);
        int qd = (int)rintf(v[p].w * inv);
        oq[p * 256 + t] = (qa & 255) | ((qb & 255) << 8) | ((qc & 255) << 16) | (qd << 24);
    }
    if (t == 0) xs[row] = am * (1.0f / 127.0f);
}

// ---- GEMM: C = (Aq . Bq^T) * xs[m] * ws[n] ------------------------------
// r8: occupancy experiment. Same merged-sync schedule as r6 (best, 235us),
// but 1024 thr = 16 waves (4M x 4N), wave tile 64x64 -> acc 64 AGPR,
// __launch_bounds__(1024,4) caps regs at 128 => 4 waves/SIMD (was 2).
// Rationale: at r6 no pipe >50% busy and 5 schedule variants tied at
// 235-242us -> latency/concurrency-bound; TLP is the untouched axis.
//
// Per tile per wave: 8 ds_read_b128 (4 A + 4 B frags) + 2 gload_lds
// (1 A-unit + 1 B-unit: 1024 lanes x 16B = full 16KB matrix tile) +
// 16 MFMA 16x16x64 + ONE vmcnt(4) + ONE barrier.
// Staging: 4 LDS buffers (tile t -> buf t&3), depth-3 (stage t+3 during t).
// vmcnt(4) at tile end leaves t+3,t+2 (4 instr/wave) in flight, forces t+1
// complete one barrier before its reads. Write-after-read: buf (t+3)&3's
// data (tile t-1) last read in iter t-1, sealed by the iter-(t-1) barrier
// all waves passed before any iter-t stage issues. Tail clamps to tile 63
// (dummy writes to never-again-read buffers). XOR chunk swizzle
// (phys = chunk ^ ((row>>1)&3)) on pre-swizzled source + read side —
// the empirically zero-conflict pattern from r4/r6.

__global__ __launch_bounds__(1024, 4) void gemm_i8_kernel(
    const int8_t* __restrict__ A,     // [M][K] i8
    const int8_t* __restrict__ B,     // [N][K] i8
    const float* __restrict__ xs,     // [M]
    const float* __restrict__ ws,     // [N]
    float* __restrict__ C)            // [M][N] fp32
{
    __shared__ __align__(16) int8_t As[4][256 * 64];   // 64 KiB
    __shared__ __align__(16) int8_t Bs[4][256 * 64];   // 64 KiB

    const int tid  = threadIdx.x;
    const int lane = tid & 63;
    const int wave = tid >> 6;         // 0..15
    const int wm   = wave >> 2;        // 0..3 -> 64 rows each
    const int wn   = wave & 3;         // 0..3 -> 64 cols each
    const int quad = lane >> 4;
    const int r16  = lane & 15;

    // T1: XCD-aware bijective swizzle. grid = 16 x 43 = 688 = 8 * 86 exactly.
    const int orig = blockIdx.x + (blockIdx.y << 4);
    const int work = (orig & 7) * 86 + (orig >> 3);
    const int m0 = (work & 15) * 256;
    const int n0 = (work >> 4) * 256;

    // staging: thread t -> LDS row t>>2 (0..255), physical chunk slot t&3,
    // source chunk pre-XOR-swizzled: slot p of row r holds chunk p^((r>>1)&3).
    const int srow   = tid >> 2;                       // 0..255
    const int schunk = (tid & 3) ^ ((tid >> 3) & 3);   // (tid>>3)&3 == (srow>>1)&3
    const int8_t* gA = A + (size_t)(m0 + srow) * K_DIM + schunk * 16;
    const int8_t* gB = B + (size_t)(n0 + srow) * K_DIM + schunk * 16;
    const int wb = wave * 1024;                        // wave-uniform LDS base

    // read side: logical chunk = quad, physical = quad ^ ((row>>1)&3)
    const int fsw   = (r16 >> 1) & 3;
    const int a_off = (wm * 64 + r16) * 64 + ((quad ^ fsw) * 16);  // + i*1024
    const int b_off = (wn * 64 + r16) * 64 + ((quad ^ fsw) * 16);  // + j*1024

    i32x4 acc[4][4];
#pragma unroll
    for (int i = 0; i < 4; i++)
#pragma unroll
        for (int j = 0; j < 4; j++) acc[i][j] = (i32x4)(0);

#define STAGE(t, buf) do {                                                    \
        direct_load16(gA + (size_t)(t) * 64, (char*)As[buf] + wb);            \
        direct_load16(gB + (size_t)(t) * 64, (char*)Bs[buf] + wb);            \
    } while (0)

    // prologue: stage tiles 0,1,2 (6 instr/wave); vmcnt(4) forces tile 0
    STAGE(0, 0); STAGE(1, 1); STAGE(2, 2);
    asm volatile("s_waitcnt vmcnt(4)" ::: "memory");
    __builtin_amdgcn_s_barrier();

    for (int t = 0; t < 64; ++t) {
        const int b  = t & 3;
        const int sb = (t + 3) & 3;
        const int s  = (t + 3 > 63) ? 63 : t + 3;

        // merged region: frag reads + stage + MFMA, no internal sync
        const int8_t* as = As[b];
        const int8_t* bs = Bs[b];
        i32x4 af[4], bf[4];
#pragma unroll
        for (int j = 0; j < 4; j++)
            bf[j] = *(const i32x4*)(bs + b_off + j * 1024);
#pragma unroll
        for (int i = 0; i < 4; i++)
            af[i] = *(const i32x4*)(as + a_off + i * 1024);

        STAGE(s, sb);

        __builtin_amdgcn_s_setprio(1);
#pragma unroll
        for (int i = 0; i < 4; i++)
#pragma unroll
            for (int j = 0; j < 4; j++)
                acc[i][j] = __builtin_amdgcn_mfma_i32_16x16x64_i8(
                    af[i], bf[j], acc[i][j], 0, 0, 0);
        __builtin_amdgcn_s_setprio(0);

        // forces tile t+1 staged-complete; leaves t+2,t+3 (4 instr) in flight
        asm volatile("s_waitcnt vmcnt(4)" ::: "memory");
        __builtin_amdgcn_s_barrier();
    }

#undef STAGE

    // epilogue: fp32 rescale by xs[m]*ws[n]; C/D frag: col=r16, row=quad*4+r
#pragma unroll
    for (int i = 0; i < 4; i++) {
        const int mrow = m0 + wm * 64 + i * 16 + quad * 4;
        float rsc[4];
#pragma unroll
        for (int r = 0; r < 4; r++) rsc[r] = xs[mrow + r];
#pragma unroll
        for (int j = 0; j < 4; j++) {
            const int n = n0 + wn * 64 + j * 16 + r16;
            const float sc = ws[n];
#pragma unroll
            for (int r = 0; r < 4; r++)
                C[(size_t)(mrow + r) * N_DIM + n] = (float)acc[i][j][r] * sc * rsc[r];
        }
    }
}

// ---- launcher ------------------------------------------------------------

extern "C" void kernel_launch(void* const* d_in, const int* in_sizes, int n_in,
                              void* d_out, int out_size, void* d_ws, size_t ws_size,
                              hipStream_t stream) {
    const float* x       = (const float*)d_in[0];   // [4096][4096]
    const int*   w_int   = (const int*)d_in[1];     // [11008][4096]
    const float* w_scale = (const float*)d_in[2];   // [11008]
    float*       out     = (float*)d_out;           // [4096][11008]

    // ws layout: Wq i8 (45,088,768 B) | Xq i8 (16,777,216 B) | xs f32 (16,384 B)
    int8_t* wq = (int8_t*)d_ws;
    int8_t* xq = (int8_t*)((char*)d_ws + (size_t)N_DIM * K_DIM);
    float*  xs = (float*)((char*)d_ws + (size_t)N_DIM * K_DIM + (size_t)M_DIM * K_DIM);

    cvt_w_kernel<<<dim3(N_DIM * K_DIM / 4 / 256), dim3(256), 0, stream>>>(w_int, wq);
    quant_x_kernel<<<dim3(M_DIM), dim3(256), 0, stream>>>(x, xq, xs);
    gemm_i8_kernel<<<dim3(M_DIM / 256, N_DIM / 256), dim3(1024), 0, stream>>>(xq, wq, xs, w_scale, out);
}